// Round 9
// baseline (117.004 us; speedup 1.0000x reference)
//
#include <hip/hip_runtime.h>
#include <hip/hip_bf16.h>

// B=4, C=64, O=64, H=W=128, K=3, KK=9, PAD=1
// MFMA 16x16x32 bf16: A[m=lane&15][k=(lane>>4)*8+j], B[n=lane&15][k=...],
// C/D: col(n)=lane&15, row(m)=(lane>>4)*4+reg
// kappa = s*32 + q*8 + j  ->  tap = s>>1, c = (s&1)*32 + q*8 + j
//
// ws layout (bytes):
//   xB  [4][128][128][64] bf16 : ofs 0        (8 MB NHWC bf16 of x)
//   Wb  [4][18][64][8]   bf16  : ofs 8388608  (deform weight B-frags)
//   OWb [2][18][64][8]   bf16  : ofs 8462336  (offset_w B-frags)

typedef short short8 __attribute__((ext_vector_type(8)));
typedef short short4v __attribute__((ext_vector_type(4)));
typedef float f32x4 __attribute__((ext_vector_type(4)));

static __device__ inline short bf16s(float f) {
    __hip_bfloat16 h = __float2bfloat16(f);
    return *(short*)&h;
}
static __device__ inline float lo2f(unsigned u) { return __uint_as_float(u << 16); }
static __device__ inline float hi2f(unsigned u) { return __uint_as_float(u & 0xffff0000u); }

// ---------------------------------------------------------------- prep (bf16 B-fragment packing)
__global__ void prep_kernel(const float* __restrict__ offset_w, // [18][64][9]
                            const float* __restrict__ weight,   // [64][64][9]
                            __hip_bfloat16* __restrict__ Wb,    // [4][18][64][8]
                            __hip_bfloat16* __restrict__ OWb)   // [2][18][64][8]
{
    int id = blockIdx.x * 256 + threadIdx.x;
    if (id < 36864) {
        int j    = id & 7;
        int lane = (id >> 3) & 63;
        int id3  = id >> 9;
        int s    = id3 % 18;
        int otile = id3 / 18;
        int n = lane & 15, q = lane >> 4;
        int kap = s * 32 + q * 8 + j;      // kappa = k*64 + c
        int k = kap >> 6, c = kap & 63;
        int o = otile * 16 + n;
        Wb[id] = __float2bfloat16(weight[(o * 64 + c) * 9 + k]);
    }
    int id2 = id - 36864;
    if (id2 >= 0 && id2 < 18432) {
        int j    = id2 & 7;
        int lane = (id2 >> 3) & 63;
        int id3  = id2 >> 9;
        int s    = id3 % 18;
        int ntile = id3 / 18;
        int n = lane & 15, q = lane >> 4;
        int kap = s * 32 + q * 8 + j;
        int k = kap >> 6, c = kap & 63;
        int o = ntile * 16 + n;
        float v = (o < 18) ? offset_w[(o * 64 + c) * 9 + k] : 0.0f;
        OWb[id2] = __float2bfloat16(v);
    }
}

// ---------------------------------------------------------------- NCHW f32 -> NHWC bf16
__global__ void transpose_kernel(const float* __restrict__ x, __hip_bfloat16* __restrict__ xB)
{
    __shared__ __align__(16) float lds[128 * 65];
    int bh = blockIdx.x;                // b*128 + h
    int b = bh >> 7, h = bh & 127;
    int t = threadIdx.x;
    int w = t & 127, chalf = t >> 7;
    for (int i = 0; i < 32; ++i) {
        int c = i * 2 + chalf;
        lds[w * 65 + c] = x[((b * 64 + c) * 128 + h) * 128 + w];
    }
    __syncthreads();
    unsigned* dst = (unsigned*)(xB + ((b * 128 + h) * 128) * 64);
    for (int i = 0; i < 16; ++i) {
        int L = i * 256 + t;            // L = ww*32 + c2
        int ww = L >> 5, c2 = L & 31;
        float f0 = lds[ww * 65 + c2 * 2];
        float f1 = lds[ww * 65 + c2 * 2 + 1];
        unsigned pk = ((unsigned)bf16s(f0) & 0xffffu) | ((unsigned)bf16s(f1) << 16);
        dst[L] = pk;
    }
}

// ---------------------------------------------------------------- fused offconv + deformable conv
// block = 16x1 row tile; 4 waves; grid = 4*128*8 = 4096
__global__ __launch_bounds__(256, 5) void deform_kernel(
    const __hip_bfloat16* __restrict__ xB,  // [4][128][128][64] NHWC bf16
    const __hip_bfloat16* __restrict__ Wb,  // [4][18][64][8]
    const __hip_bfloat16* __restrict__ OWb, // [2][18][64][8]
    const float* __restrict__ offset_b,     // [18]
    const float* __restrict__ bias,         // [64]
    float* __restrict__ out)                // [4][64][128][128] NCHW
{
    __shared__ __align__(16) short sampB[18 * 16 * 40];  // 23040 B; shorts 0..4319 alias patch[54][80]
    __shared__ __align__(16) float offL[288];            // [o][p]  (separate array — NOT aliased)
    __shared__ __align__(16) int   PCo[144][4];          // clamped corner element-offsets
    __shared__ __align__(16) float PCw[144][4];          // masked bilinear weights

    int t = threadIdx.x, wv = t >> 6, lane = t & 63;
    int bid = blockIdx.x;            // b*1024 + h*8 + tx
    int b  = bid >> 10;
    int h  = (bid >> 3) & 127;
    int w0 = (bid & 7) << 4;

    short* patch = sampB;            // [54 px][80 shorts]; px = row*18+col (rows h-1..h+1, cols w0-1..w0+16)

    // ---- phase 1: stage 3x18x64 patch bf16 (zero-padded at borders)
    {
        int c2 = t & 31, pg = t >> 5;
        const __hip_bfloat16* xbb = xB + b * (128 * 128 * 64) + c2 * 2;
#pragma unroll
        for (int i = 0; i < 7; ++i) {
            int pix = i * 8 + pg;
            if (pix < 54) {
                int row = pix / 18, col = pix - row * 18;
                int hh = h - 1 + row, ww2 = w0 - 1 + col;
                unsigned v = 0;
                if (hh >= 0 && hh < 128 && ww2 >= 0 && ww2 < 128)
                    v = *(const unsigned*)(xbb + (hh * 128 + ww2) * 64);
                *(unsigned*)&patch[pix * 80 + c2 * 2] = v;
            }
        }
    }
    __syncthreads();

    // ---- phase 2: offset conv via MFMA (waves 0,1; o = wv*16+n; pixel p = q*4+reg)
    if (wv < 2) {
        int n = lane & 15, q = lane >> 4;
        const short8* Bw = (const short8*)OWb + (wv * 18) * 64 + lane;
        f32x4 acc = {0.f, 0.f, 0.f, 0.f};
#pragma unroll
        for (int s = 0; s < 18; ++s) {
            int k = s >> 1;
            int ky = k / 3, kx = k - ky * 3;
            int pix = ky * 18 + n + kx;
            const short8 a = *(const short8*)&patch[pix * 80 + (s & 1) * 32 + q * 8];
            acc = __builtin_amdgcn_mfma_f32_16x16x32_bf16(a, Bw[s * 64], acc, 0, 0, 0);
        }
        int o = wv * 16 + n;
        if (o < 18) {
            float bo = offset_b[o];
#pragma unroll
            for (int r = 0; r < 4; ++r)
                offL[o * 16 + q * 4 + r] = acc[r] + bo;
        }
    }
    __syncthreads();

    // ---- phase 3: per-(pixel,tap) precompute, balanced across all 4 waves (36 items/wave)
    if (lane < 36) {
        int i3 = wv * 36 + lane;         // 0..143
        int p = i3 / 9, k = i3 - p * 9;
        float offy = offL[(2 * k) * 16 + p];
        float offx = offL[(2 * k + 1) * 16 + p];
        float py = (float)(h - 1 + (k / 3)) + offy;
        float px = (float)(w0 + p - 1 + (k % 3)) + offx;
        float y0f = floorf(py), x0f = floorf(px);
        float wy1 = py - y0f, wx1 = px - x0f;
        float wy0 = 1.0f - wy1, wx0 = 1.0f - wx1;
        int iy = (int)y0f, ix = (int)x0f;
        bool y0v = (iy >= 0) && (iy < 128);
        bool y1v = (iy >= -1) && (iy < 127);
        bool x0v = (ix >= 0) && (ix < 128);
        bool x1v = (ix >= -1) && (ix < 127);
        int iy0c = min(max(iy, 0), 127), iy1c = min(max(iy + 1, 0), 127);
        int ix0c = min(max(ix, 0), 127), ix1c = min(max(ix + 1, 0), 127);
        PCo[i3][0] = (iy0c * 128 + ix0c) * 64;
        PCo[i3][1] = (iy0c * 128 + ix1c) * 64;
        PCo[i3][2] = (iy1c * 128 + ix0c) * 64;
        PCo[i3][3] = (iy1c * 128 + ix1c) * 64;
        PCw[i3][0] = (y0v && x0v) ? wy0 * wx0 : 0.0f;
        PCw[i3][1] = (y0v && x1v) ? wy0 * wx1 : 0.0f;
        PCw[i3][2] = (y1v && x0v) ? wy1 * wx0 : 0.0f;
        PCw[i3][3] = (y1v && x1v) ? wy1 * wx1 : 0.0f;
    }
    __syncthreads();

    // ---- phase 4: sampling, register-blocked: 3 chunks x 3 taps, 12 gathers in flight/chunk
    {
        int g = lane >> 4, c4 = lane & 15;
        int p = wv * 4 + g;
        const __hip_bfloat16* xb4 = xB + b * (128 * 128 * 64) + c4 * 4;
#pragma unroll
        for (int kc = 0; kc < 3; ++kc) {
            int4   ofs[3];
            float4 ww[3];
            uint2  r[3][4];
#pragma unroll
            for (int j = 0; j < 3; ++j) {
                int pr = p * 9 + kc * 3 + j;
                ofs[j] = *(const int4*)&PCo[pr][0];
                ww[j]  = *(const float4*)&PCw[pr][0];
            }
#pragma unroll
            for (int j = 0; j < 3; ++j) {
                r[j][0] = *(const uint2*)(xb4 + ofs[j].x);
                r[j][1] = *(const uint2*)(xb4 + ofs[j].y);
                r[j][2] = *(const uint2*)(xb4 + ofs[j].z);
                r[j][3] = *(const uint2*)(xb4 + ofs[j].w);
            }
#pragma unroll
            for (int j = 0; j < 3; ++j) {
                int k = kc * 3 + j;
                float s0 = fmaf(ww[j].w, lo2f(r[j][3].x), fmaf(ww[j].z, lo2f(r[j][2].x), fmaf(ww[j].y, lo2f(r[j][1].x), ww[j].x * lo2f(r[j][0].x))));
                float s1 = fmaf(ww[j].w, hi2f(r[j][3].x), fmaf(ww[j].z, hi2f(r[j][2].x), fmaf(ww[j].y, hi2f(r[j][1].x), ww[j].x * hi2f(r[j][0].x))));
                float s2 = fmaf(ww[j].w, lo2f(r[j][3].y), fmaf(ww[j].z, lo2f(r[j][2].y), fmaf(ww[j].y, lo2f(r[j][1].y), ww[j].x * lo2f(r[j][0].y))));
                float s3 = fmaf(ww[j].w, hi2f(r[j][3].y), fmaf(ww[j].z, hi2f(r[j][2].y), fmaf(ww[j].y, hi2f(r[j][1].y), ww[j].x * hi2f(r[j][0].y))));
                int s = 2 * k + (c4 >> 3);
                short4v pk = { bf16s(s0), bf16s(s1), bf16s(s2), bf16s(s3) };
                *(short4v*)&sampB[(s * 16 + p) * 40 + (c4 & 7) * 4] = pk;
            }
        }
    }
    __syncthreads();

    // ---- phase 5: einsum via MFMA; wave wv = o-tile; 18 K-steps
    {
        int n = lane & 15, q = lane >> 4;
        int arow = n * 40 + q * 8;          // A: m = pixel = lane&15
        const short8* BwW = (const short8*)Wb + (wv * 18) * 64 + lane;
        f32x4 acc = {0.f, 0.f, 0.f, 0.f};
#pragma unroll
        for (int s = 0; s < 18; ++s) {
            const short8 a = *(const short8*)&sampB[s * 640 + arow];
            acc = __builtin_amdgcn_mfma_f32_16x16x32_bf16(a, BwW[s * 64], acc, 0, 0, 0);
        }
        int o = wv * 16 + n;
        float bo = bias[o];
        // C/D: col = o, row m = q*4+reg = pixel -> w = w0 + q*4 + reg (full 64B lines per o)
        float4 st = {acc[0] + bo, acc[1] + bo, acc[2] + bo, acc[3] + bo};
        *(float4*)&out[((b * 64 + o) * 128 + h) * 128 + w0 + q * 4] = st;
    }
}

// ---------------------------------------------------------------- launch
extern "C" void kernel_launch(void* const* d_in, const int* in_sizes, int n_in,
                              void* d_out, int out_size, void* d_ws, size_t ws_size,
                              hipStream_t stream) {
    const float* x        = (const float*)d_in[0];
    const float* offset_w = (const float*)d_in[1];
    const float* offset_b = (const float*)d_in[2];
    const float* weight   = (const float*)d_in[3];
    const float* bias     = (const float*)d_in[4];
    char* ws = (char*)d_ws;
    __hip_bfloat16* xB  = (__hip_bfloat16*)ws;                     // 8388608 B
    __hip_bfloat16* Wb  = (__hip_bfloat16*)(ws + 8388608);         // 73728 B
    __hip_bfloat16* OWb = (__hip_bfloat16*)(ws + 8388608 + 73728); // 36864 B
    float* outp = (float*)d_out;

    hipLaunchKernelGGL(prep_kernel,      dim3(216),  dim3(256), 0, stream, offset_w, weight, Wb, OWb);
    hipLaunchKernelGGL(transpose_kernel, dim3(512),  dim3(256), 0, stream, x, xB);
    hipLaunchKernelGGL(deform_kernel,    dim3(4096), dim3(256), 0, stream, xB, Wb, OWb, offset_b, bias, outp);
}

// Round 10
// 115.125 us; speedup vs baseline: 1.0163x; 1.0163x over previous
//
#include <hip/hip_runtime.h>
#include <hip/hip_bf16.h>

// B=4, C=64, O=64, H=W=128, K=3, KK=9, PAD=1
// MFMA 16x16x32 bf16: A[m=lane&15][k=(lane>>4)*8+j], B[n=lane&15][k=...],
// C/D: col(n)=lane&15, row(m)=(lane>>4)*4+reg
// kappa = s*32 + q*8 + j  ->  tap = s>>1, c = (s&1)*32 + q*8 + j
//
// ws layout (bytes):
//   xB  [4][128][128][64] bf16 : ofs 0        (8 MB NHWC bf16 of x)
//   Wb  [4][18][64][8]   bf16  : ofs 8388608  (deform weight B-frags)
//   OWb [2][18][64][8]   bf16  : ofs 8462336  (offset_w B-frags)

typedef short short8 __attribute__((ext_vector_type(8)));
typedef short short4v __attribute__((ext_vector_type(4)));
typedef float f32x4 __attribute__((ext_vector_type(4)));

static __device__ inline short bf16s(float f) {
    __hip_bfloat16 h = __float2bfloat16(f);
    return *(short*)&h;
}
static __device__ inline float lo2f(unsigned u) { return __uint_as_float(u << 16); }
static __device__ inline float hi2f(unsigned u) { return __uint_as_float(u & 0xffff0000u); }

// ---------------------------------------------------------------- prep (bf16 B-fragment packing)
__global__ void prep_kernel(const float* __restrict__ offset_w, // [18][64][9]
                            const float* __restrict__ weight,   // [64][64][9]
                            __hip_bfloat16* __restrict__ Wb,    // [4][18][64][8]
                            __hip_bfloat16* __restrict__ OWb)   // [2][18][64][8]
{
    int id = blockIdx.x * 256 + threadIdx.x;
    if (id < 36864) {
        int j    = id & 7;
        int lane = (id >> 3) & 63;
        int id3  = id >> 9;
        int s    = id3 % 18;
        int otile = id3 / 18;
        int n = lane & 15, q = lane >> 4;
        int kap = s * 32 + q * 8 + j;      // kappa = k*64 + c
        int k = kap >> 6, c = kap & 63;
        int o = otile * 16 + n;
        Wb[id] = __float2bfloat16(weight[(o * 64 + c) * 9 + k]);
    }
    int id2 = id - 36864;
    if (id2 >= 0 && id2 < 18432) {
        int j    = id2 & 7;
        int lane = (id2 >> 3) & 63;
        int id3  = id2 >> 9;
        int s    = id3 % 18;
        int ntile = id3 / 18;
        int n = lane & 15, q = lane >> 4;
        int kap = s * 32 + q * 8 + j;
        int k = kap >> 6, c = kap & 63;
        int o = ntile * 16 + n;
        float v = (o < 18) ? offset_w[(o * 64 + c) * 9 + k] : 0.0f;
        OWb[id2] = __float2bfloat16(v);
    }
}

// ---------------------------------------------------------------- NCHW f32 -> NHWC bf16
__global__ void transpose_kernel(const float* __restrict__ x, __hip_bfloat16* __restrict__ xB)
{
    __shared__ __align__(16) float lds[128 * 65];
    int bh = blockIdx.x;                // b*128 + h
    int b = bh >> 7, h = bh & 127;
    int t = threadIdx.x;
    int w = t & 127, chalf = t >> 7;
    for (int i = 0; i < 32; ++i) {
        int c = i * 2 + chalf;
        lds[w * 65 + c] = x[((b * 64 + c) * 128 + h) * 128 + w];
    }
    __syncthreads();
    unsigned* dst = (unsigned*)(xB + ((b * 128 + h) * 128) * 64);
    for (int i = 0; i < 16; ++i) {
        int L = i * 256 + t;            // L = ww*32 + c2
        int ww = L >> 5, c2 = L & 31;
        float f0 = lds[ww * 65 + c2 * 2];
        float f1 = lds[ww * 65 + c2 * 2 + 1];
        unsigned pk = ((unsigned)bf16s(f0) & 0xffffu) | ((unsigned)bf16s(f1) << 16);
        dst[L] = pk;
    }
}

// ---------------------------------------------------------------- fused offconv + deformable conv
// block = 16x1 row tile; 4 waves; grid = 4*128*8 = 4096
// LDS = sampB 23040 + offL 1152 = 24192 B -> 6 blocks/CU
__global__ __launch_bounds__(256, 6) void deform_kernel(
    const __hip_bfloat16* __restrict__ xB,  // [4][128][128][64] NHWC bf16
    const __hip_bfloat16* __restrict__ Wb,  // [4][18][64][8]
    const __hip_bfloat16* __restrict__ OWb, // [2][18][64][8]
    const float* __restrict__ offset_b,     // [18]
    const float* __restrict__ bias,         // [64]
    float* __restrict__ out)                // [4][64][128][128] NCHW
{
    __shared__ __align__(16) short sampB[18 * 16 * 40];  // 23040 B; shorts 0..4319 alias patch[54][80]
    __shared__ __align__(16) float offL[288];            // [o][p]  (separate array — NOT aliased)

    int t = threadIdx.x, wv = t >> 6, lane = t & 63;
    int bid = blockIdx.x;            // b*1024 + h*8 + tx
    int b  = bid >> 10;
    int h  = (bid >> 3) & 127;
    int w0 = (bid & 7) << 4;

    short* patch = sampB;            // [54 px][80 shorts]; px = row*18+col (rows h-1..h+1, cols w0-1..w0+16)

    // ---- phase 1: stage 3x18x64 patch bf16 (zero-padded at borders)
    {
        int c2 = t & 31, pg = t >> 5;
        const __hip_bfloat16* xbb = xB + b * (128 * 128 * 64) + c2 * 2;
#pragma unroll
        for (int i = 0; i < 7; ++i) {
            int pix = i * 8 + pg;
            if (pix < 54) {
                int row = pix / 18, col = pix - row * 18;
                int hh = h - 1 + row, ww2 = w0 - 1 + col;
                unsigned v = 0;
                if (hh >= 0 && hh < 128 && ww2 >= 0 && ww2 < 128)
                    v = *(const unsigned*)(xbb + (hh * 128 + ww2) * 64);
                *(unsigned*)&patch[pix * 80 + c2 * 2] = v;
            }
        }
    }
    __syncthreads();

    // ---- phase 2: offset conv via MFMA (waves 0,1; o = wv*16+n; pixel p = q*4+reg)
    if (wv < 2) {
        int n = lane & 15, q = lane >> 4;
        const short8* Bw = (const short8*)OWb + (wv * 18) * 64 + lane;
        f32x4 acc = {0.f, 0.f, 0.f, 0.f};
#pragma unroll
        for (int s = 0; s < 18; ++s) {
            int k = s >> 1;
            int ky = k / 3, kx = k - ky * 3;
            int pix = ky * 18 + n + kx;
            const short8 a = *(const short8*)&patch[pix * 80 + (s & 1) * 32 + q * 8];
            acc = __builtin_amdgcn_mfma_f32_16x16x32_bf16(a, Bw[s * 64], acc, 0, 0, 0);
        }
        int o = wv * 16 + n;
        if (o < 18) {
            float bo = offset_b[o];
#pragma unroll
            for (int r = 0; r < 4; ++r)
                offL[o * 16 + q * 4 + r] = acc[r] + bo;
        }
    }
    __syncthreads();

    // ---- phase 4: sampling; 16-lane group g owns pixel p=wv*4+g; lane c4 owns ch 4c4..4c4+3
    // All per-tap params in REGISTERS (offL read once) -> no LDS reads inside gather loop,
    // so the 36 global gathers can be software-pipelined without lgkm serialization.
    {
        int g = lane >> 4, c4 = lane & 15;
        int p = wv * 4 + g;
        const __hip_bfloat16* xb4 = xB + b * (128 * 128 * 64) + c4 * 4;

        float offy[9], offx[9];
#pragma unroll
        for (int k = 0; k < 9; ++k) {
            offy[k] = offL[(2 * k) * 16 + p];
            offx[k] = offL[(2 * k + 1) * 16 + p];
        }

#pragma unroll
        for (int k = 0; k < 9; ++k) {
            float py = (float)(h - 1 + (k / 3)) + offy[k];
            float px = (float)(w0 + p - 1 + (k % 3)) + offx[k];
            float y0f = floorf(py), x0f = floorf(px);
            float wy1 = py - y0f, wx1 = px - x0f;
            float wy0 = 1.0f - wy1, wx0 = 1.0f - wx1;
            int iy = (int)y0f, ix = (int)x0f;
            bool y0v = (iy >= 0) && (iy < 128);
            bool y1v = (iy >= -1) && (iy < 127);
            bool x0v = (ix >= 0) && (ix < 128);
            bool x1v = (ix >= -1) && (ix < 127);
            int iy0c = min(max(iy, 0), 127), iy1c = min(max(iy + 1, 0), 127);
            int ix0c = min(max(ix, 0), 127), ix1c = min(max(ix + 1, 0), 127);
            int e00 = (iy0c * 128 + ix0c) * 64;
            int e01 = (iy0c * 128 + ix1c) * 64;
            int e10 = (iy1c * 128 + ix0c) * 64;
            int e11 = (iy1c * 128 + ix1c) * 64;
            float wa = (y0v && x0v) ? wy0 * wx0 : 0.0f;
            float wb_ = (y0v && x1v) ? wy0 * wx1 : 0.0f;
            float wc = (y1v && x0v) ? wy1 * wx0 : 0.0f;
            float wd = (y1v && x1v) ? wy1 * wx1 : 0.0f;

            uint2 r0 = *(const uint2*)(xb4 + e00);
            uint2 r1 = *(const uint2*)(xb4 + e01);
            uint2 r2 = *(const uint2*)(xb4 + e10);
            uint2 r3 = *(const uint2*)(xb4 + e11);

            float s0 = fmaf(wd, lo2f(r3.x), fmaf(wc, lo2f(r2.x), fmaf(wb_, lo2f(r1.x), wa * lo2f(r0.x))));
            float s1 = fmaf(wd, hi2f(r3.x), fmaf(wc, hi2f(r2.x), fmaf(wb_, hi2f(r1.x), wa * hi2f(r0.x))));
            float s2 = fmaf(wd, lo2f(r3.y), fmaf(wc, lo2f(r2.y), fmaf(wb_, lo2f(r1.y), wa * lo2f(r0.y))));
            float s3 = fmaf(wd, hi2f(r3.y), fmaf(wc, hi2f(r2.y), fmaf(wb_, hi2f(r1.y), wa * hi2f(r0.y))));
            int s = 2 * k + (c4 >> 3);
            short4v pk = { bf16s(s0), bf16s(s1), bf16s(s2), bf16s(s3) };
            *(short4v*)&sampB[(s * 16 + p) * 40 + (c4 & 7) * 4] = pk;
        }
    }
    __syncthreads();

    // ---- phase 5: einsum via MFMA; wave wv = o-tile; 18 K-steps
    {
        int n = lane & 15, q = lane >> 4;
        int arow = n * 40 + q * 8;          // A: m = pixel = lane&15
        const short8* BwW = (const short8*)Wb + (wv * 18) * 64 + lane;
        f32x4 acc = {0.f, 0.f, 0.f, 0.f};
#pragma unroll
        for (int s = 0; s < 18; ++s) {
            const short8 a = *(const short8*)&sampB[s * 640 + arow];
            acc = __builtin_amdgcn_mfma_f32_16x16x32_bf16(a, BwW[s * 64], acc, 0, 0, 0);
        }
        int o = wv * 16 + n;
        float bo = bias[o];
        // C/D: col = o, row m = q*4+reg = pixel -> w = w0 + q*4 + reg (full 64B lines per o)
        float4 st = {acc[0] + bo, acc[1] + bo, acc[2] + bo, acc[3] + bo};
        *(float4*)&out[((b * 64 + o) * 128 + h) * 128 + w0 + q * 4] = st;
    }
}

// ---------------------------------------------------------------- launch
extern "C" void kernel_launch(void* const* d_in, const int* in_sizes, int n_in,
                              void* d_out, int out_size, void* d_ws, size_t ws_size,
                              hipStream_t stream) {
    const float* x        = (const float*)d_in[0];
    const float* offset_w = (const float*)d_in[1];
    const float* offset_b = (const float*)d_in[2];
    const float* weight   = (const float*)d_in[3];
    const float* bias     = (const float*)d_in[4];
    char* ws = (char*)d_ws;
    __hip_bfloat16* xB  = (__hip_bfloat16*)ws;                     // 8388608 B
    __hip_bfloat16* Wb  = (__hip_bfloat16*)(ws + 8388608);         // 73728 B
    __hip_bfloat16* OWb = (__hip_bfloat16*)(ws + 8388608 + 73728); // 36864 B
    float* outp = (float*)d_out;

    hipLaunchKernelGGL(prep_kernel,      dim3(216),  dim3(256), 0, stream, offset_w, weight, Wb, OWb);
    hipLaunchKernelGGL(transpose_kernel, dim3(512),  dim3(256), 0, stream, x, xB);
    hipLaunchKernelGGL(deform_kernel,    dim3(4096), dim3(256), 0, stream, xB, Wb, OWb, offset_b, bias, outp);
}